// Round 12
// baseline (622.581 us; speedup 1.0000x reference)
//
#include <hip/hip_runtime.h>
#include <math.h>

// ---------------------------------------------------------------------------
// AFPNNet: masked features -> {2-layer GAT, 2-layer GCN} -> concat(encoded)
//          -> recon = relu(enc@Wdec+b), disc = (sigmoid(relu(enc@Wd1+b)@Wd2+b))@Wd3+b
// Outputs flat: recon [N*128] | encoded [N*128] | disc [N]
// h layout: interleaved [N][128] = [h_gat(64) | h_gcn*dinv_src(64)], 512 B/row.
// csr stores BYTE offsets (src*512).
// LESSON (r4-r7): global weight loads in const-trip k-loops are either hoisted
//   (spill) or sunk (serialized) by the scheduler -> stage weights in LDS.
// LESSON (r8/r9): k_fill 16x write amplification = cross-XCD dirty-line
//   replication -> dst-shard by blockIdx&7 (one XCD per csr region). Fixed.
// LESSON (r9): 2-pass dense3 for occupancy REGRESSED (125->149) — restage +
//   barriers + 2x enc reads cost more than 2 blocks/CU bought.
// r12: dense3 stays 1 block/CU but the A+B main loop loses its GLOBAL enc
//   loads: enc tile (32KB) staged in LDS once (coalesced), sd1 aliases it.
//   Main loop = pure LDS+VALU; ds_read latency hidden by unroll-2.
// ---------------------------------------------------------------------------

#define INF_F __int_as_float(0x7f800000)
#define NSHARD 8

__device__ __forceinline__ long edge_at(const void* p, int is64, long i) {
    if (is64) return (long)((const long long*)p)[i];
    return (long)((const int*)p)[i];
}

__global__ void k_detect(const int* ew, long words, int* flag) {
    long t = (long)blockIdx.x * blockDim.x + threadIdx.x;
    long stride = words / 8192; if (stride < 1) stride = 1;
    long w = 2 * (t * stride) + 1;
    if (t < 4096 && w < words) {
        if (ew[w] != 0) atomicOr(flag, 1);
    }
}

__global__ void k_deg(const void* edges, long E, const int* flag, int* deg) {
    long e = (long)blockIdx.x * blockDim.x + threadIdx.x;
    if (e >= E) return;
    int is64 = (*flag == 0);
    int d = (int)edge_at(edges, is64, E + e);
    atomicAdd(&deg[d], 1);
}

__global__ void k_scanA(const int* deg, int N, int* offs, int* blockSums) {
    __shared__ int s[256];
    int t = threadIdx.x;
    int i = blockIdx.x * 256 + t;
    int v = (i < N) ? deg[i] : 0;
    s[t] = v;
    for (int off = 1; off < 256; off <<= 1) {
        __syncthreads();
        int u = (t >= off) ? s[t - off] : 0;
        __syncthreads();
        s[t] += u;
    }
    __syncthreads();
    if (i < N) offs[i] = s[t] - v;
    if (t == 255) blockSums[blockIdx.x] = s[255];
}

__global__ void k_scanB(const int* blockSums, int nb, int* blockOff) {
    __shared__ int s[1024];
    int t = threadIdx.x;
    int v = (t < nb) ? blockSums[t] : 0;
    s[t] = v;
    for (int off = 1; off < 1024; off <<= 1) {
        __syncthreads();
        int u = (t >= off) ? s[t - off] : 0;
        __syncthreads();
        s[t] += u;
    }
    __syncthreads();
    if (t < nb) blockOff[t] = s[t] - v;
}

__global__ void k_scanC(int* offs, const int* blockOff, const int* deg,
                        float* dinv, int N, long E) {
    int i = blockIdx.x * 256 + threadIdx.x;
    if (i < N) {
        offs[i] += blockOff[i >> 8];
        int dg = deg[i];
        dinv[i] = dg > 0 ? rsqrtf((float)dg) : 0.0f;
    }
    if (i == 0) offs[N] = (int)E;
}

// XCD-sharded CSR fill (see header LESSON r8/r9).
__global__ void k_fill(const void* edges, long E, const int* flag,
                       const int* offs, int* cursor, int* csr_src, int npp) {
    int bid = blockIdx.x;
    int shard = bid & (NSHARD - 1);
    long e = (long)(bid >> 3) * blockDim.x + threadIdx.x;
    if (e >= E) return;
    int is64 = (*flag == 0);
    int d = (int)edge_at(edges, is64, E + e);
    if (d / npp != shard) return;
    int s = (int)edge_at(edges, is64, e);
    int pos = offs[d] + atomicAdd(&cursor[d], 1);
    csr_src[pos] = s << 9;                 // byte offset into [N][128] f32 rows
}

// Dense layer 1: K=128 -> h[gn][0:64]=x@Wa, h[gn][64:128]=(x@Wg)*dinv[gn].
__global__ __launch_bounds__(512) void k_dense1(
    const float* __restrict__ x, const int* __restrict__ mask,
    const float* __restrict__ Wa, const float* __restrict__ Wg,
    const float* __restrict__ aSrc, const float* __restrict__ aDst,
    const float* __restrict__ dinv,
    float* __restrict__ h,
    float* __restrict__ a_s, float* __restrict__ a_d, int N)
{
    __shared__ float sW[8192 + 16 + 8192];         // Wa | pad | Wg, 64.1 KB
    int t = threadIdx.x;
    for (int i = t; i < 2048; i += 512) {
        ((float4*)sW)[i] = ((const float4*)Wa)[i];
        ((float4*)(sW + 8208))[i] = ((const float4*)Wg)[i];
    }
    __syncthreads();
    int base = blockIdx.x * 64;
    int tx = t & 31, ny = t >> 5;                  // 16 groups x 4 nodes
    bool gat = tx < 16;
    int jc = (tx & 15) * 4;
    const float* Wp = gat ? sW : (sW + 8208);
    int gn0 = base + ny * 4;
    const float4* xp[4]; float mz[4];
#pragma unroll
    for (int n = 0; n < 4; ++n) {
        int gn = gn0 + n;
        int cl = (gn < N) ? gn : 0;
        xp[n] = (const float4*)(x + (long)cl * 128);
        mz[n] = (gn < N && mask[cl] != 1) ? 1.f : 0.f;
    }
    float acc[4][4];
#pragma unroll
    for (int n = 0; n < 4; ++n) { acc[n][0] = acc[n][1] = acc[n][2] = acc[n][3] = 0.f; }
#pragma unroll 2
    for (int k0 = 0; k0 < 128; k0 += 4) {
        float4 w[4];
#pragma unroll
        for (int kk = 0; kk < 4; ++kk) w[kk] = *(const float4*)&Wp[(k0 + kk) * 64 + jc];
        float4 xr[4];
#pragma unroll
        for (int n = 0; n < 4; ++n) xr[n] = xp[n][k0 >> 2];
#pragma unroll
        for (int kk = 0; kk < 4; ++kk) {
#pragma unroll
            for (int n = 0; n < 4; ++n) {
                float xv = (&xr[n].x)[kk];
                acc[n][0] = fmaf(xv, w[kk].x, acc[n][0]);
                acc[n][1] = fmaf(xv, w[kk].y, acc[n][1]);
                acc[n][2] = fmaf(xv, w[kk].z, acc[n][2]);
                acc[n][3] = fmaf(xv, w[kk].w, acc[n][3]);
            }
        }
    }
#pragma unroll
    for (int n = 0; n < 4; ++n) {
        acc[n][0] *= mz[n]; acc[n][1] *= mz[n]; acc[n][2] *= mz[n]; acc[n][3] *= mz[n];
    }
    float4 as4 = make_float4(0.f, 0.f, 0.f, 0.f), ad4 = as4;
    if (gat) { as4 = *(const float4*)&aSrc[jc]; ad4 = *(const float4*)&aDst[jc]; }
#pragma unroll
    for (int n = 0; n < 4; ++n) {
        int gn = gn0 + n;
        float pa = acc[n][0] * as4.x + acc[n][1] * as4.y + acc[n][2] * as4.z + acc[n][3] * as4.w;
        float pd = acc[n][0] * ad4.x + acc[n][1] * ad4.y + acc[n][2] * ad4.z + acc[n][3] * ad4.w;
#pragma unroll
        for (int off = 8; off; off >>= 1) { pa += __shfl_xor(pa, off); pd += __shfl_xor(pd, off); }
        if (gn < N) {
            if (gat) {
                if (tx == 0) { a_s[gn] = pa; a_d[gn] = pd; }
                *(float4*)&h[(long)gn * 128 + jc] =
                    make_float4(acc[n][0], acc[n][1], acc[n][2], acc[n][3]);
            } else {
                float dv = dinv[gn];
                *(float4*)&h[(long)gn * 128 + 64 + jc] =
                    make_float4(acc[n][0] * dv, acc[n][1] * dv, acc[n][2] * dv, acc[n][3] * dv);
            }
        }
    }
}

// Dense layer 2: input o interleaved [N][128], K=64 per branch. Weights in LDS.
__global__ __launch_bounds__(512) void k_dense2(
    const float* __restrict__ o,
    const float* __restrict__ Wa, const float* __restrict__ Wg,
    const float* __restrict__ aSrc, const float* __restrict__ aDst,
    const float* __restrict__ dinv,
    float* __restrict__ h,
    float* __restrict__ a_s, float* __restrict__ a_d, int N)
{
    __shared__ float sW[4096 + 16 + 4096];         // Wa | pad | Wg, 32.1 KB
    int t = threadIdx.x;
    for (int i = t; i < 1024; i += 512) {
        ((float4*)sW)[i] = ((const float4*)Wa)[i];
        ((float4*)(sW + 4112))[i] = ((const float4*)Wg)[i];
    }
    __syncthreads();
    int base = blockIdx.x * 64;
    int tx = t & 31, ny = t >> 5;
    bool gat = tx < 16;
    int jc = (tx & 15) * 4;
    const float* Wp = gat ? sW : (sW + 4112);
    int xoff = gat ? 0 : 16;                       // float4 offset into o row
    int gn0 = base + ny * 4;
    const float4* xp[4];
#pragma unroll
    for (int n = 0; n < 4; ++n) {
        int gn = gn0 + n;
        int cl = (gn < N) ? gn : 0;
        xp[n] = (const float4*)(o + (long)cl * 128) + xoff;
    }
    float acc[4][4];
#pragma unroll
    for (int n = 0; n < 4; ++n) { acc[n][0] = acc[n][1] = acc[n][2] = acc[n][3] = 0.f; }
#pragma unroll 2
    for (int k0 = 0; k0 < 64; k0 += 4) {
        float4 w[4];
#pragma unroll
        for (int kk = 0; kk < 4; ++kk) w[kk] = *(const float4*)&Wp[(k0 + kk) * 64 + jc];
        float4 xr[4];
#pragma unroll
        for (int n = 0; n < 4; ++n) xr[n] = xp[n][k0 >> 2];
#pragma unroll
        for (int kk = 0; kk < 4; ++kk) {
#pragma unroll
            for (int n = 0; n < 4; ++n) {
                float xv = (&xr[n].x)[kk];
                acc[n][0] = fmaf(xv, w[kk].x, acc[n][0]);
                acc[n][1] = fmaf(xv, w[kk].y, acc[n][1]);
                acc[n][2] = fmaf(xv, w[kk].z, acc[n][2]);
                acc[n][3] = fmaf(xv, w[kk].w, acc[n][3]);
            }
        }
    }
    float4 as4 = make_float4(0.f, 0.f, 0.f, 0.f), ad4 = as4;
    if (gat) { as4 = *(const float4*)&aSrc[jc]; ad4 = *(const float4*)&aDst[jc]; }
#pragma unroll
    for (int n = 0; n < 4; ++n) {
        int gn = gn0 + n;
        float pa = acc[n][0] * as4.x + acc[n][1] * as4.y + acc[n][2] * as4.z + acc[n][3] * as4.w;
        float pd = acc[n][0] * ad4.x + acc[n][1] * ad4.y + acc[n][2] * ad4.z + acc[n][3] * ad4.w;
#pragma unroll
        for (int off = 8; off; off >>= 1) { pa += __shfl_xor(pa, off); pd += __shfl_xor(pd, off); }
        if (gn < N) {
            if (gat) {
                if (tx == 0) { a_s[gn] = pa; a_d[gn] = pd; }
                *(float4*)&h[(long)gn * 128 + jc] =
                    make_float4(acc[n][0], acc[n][1], acc[n][2], acc[n][3]);
            } else {
                float dv = dinv[gn];
                *(float4*)&h[(long)gn * 128 + 64 + jc] =
                    make_float4(acc[n][0] * dv, acc[n][1] * dv, acc[n][2] * dv, acc[n][3] * dv);
            }
        }
    }
}

// Fused aggregation, wave per dst node (unchanged).
template <int MODE>   // 0: layer1 (ELU/ReLU), 1: layer2 (plain)
__global__ __launch_bounds__(512) void k_agg(
    const int* __restrict__ offs, const int* __restrict__ csr,
    const float* __restrict__ a_s, const float* __restrict__ a_d,
    const float* __restrict__ dinv,
    const float* __restrict__ h,
    const float* __restrict__ b_a, const float* __restrict__ b_g,
    float* __restrict__ out, int N)
{
    int node = blockIdx.x * 8 + (threadIdx.x >> 6);
    int lane = threadIdx.x & 63;
    if (node >= N) return;
    int p0 = offs[node], p1 = offs[node + 1];
    int deg = p1 - p0;
    float adst = a_d[node];
    float dv = dinv[node];
    bool gat = lane < 32;
    const char* hb = (const char*)h + lane * 8;

    float2 res = make_float2(0.f, 0.f);
    if (deg > 0 && deg <= 64) {
        int soff = (lane < deg) ? csr[p0 + lane] : 0;
        float att = -INF_F;
        if (lane < deg) {
            float a = a_s[soff >> 9] + adst;
            att = a >= 0.f ? a : 0.2f * a;
        }
        float m = att;
#pragma unroll
        for (int off = 32; off; off >>= 1) m = fmaxf(m, __shfl_xor(m, off));
        float w = (lane < deg) ? __expf(att - m) : 0.f;
        float den = w;
#pragma unroll
        for (int off = 32; off; off >>= 1) den += __shfl_xor(den, off);
        float coef = w / den;

        float2 a0 = make_float2(0.f, 0.f), a1 = a0, a2 = a0, a3 = a0;
        int e = 0;
        for (; e + 4 <= deg; e += 4) {
            int o0 = __shfl(soff, e),     o1 = __shfl(soff, e + 1);
            int o2 = __shfl(soff, e + 2), o3 = __shfl(soff, e + 3);
            float c0 = __shfl(coef, e),     c1 = __shfl(coef, e + 1);
            float c2 = __shfl(coef, e + 2), c3 = __shfl(coef, e + 3);
            float2 v0 = *(const float2*)(hb + o0);
            float2 v1 = *(const float2*)(hb + o1);
            float2 v2 = *(const float2*)(hb + o2);
            float2 v3 = *(const float2*)(hb + o3);
            float w0 = gat ? c0 : 1.f, w1 = gat ? c1 : 1.f;
            float w2 = gat ? c2 : 1.f, w3 = gat ? c3 : 1.f;
            a0.x = fmaf(v0.x, w0, a0.x); a0.y = fmaf(v0.y, w0, a0.y);
            a1.x = fmaf(v1.x, w1, a1.x); a1.y = fmaf(v1.y, w1, a1.y);
            a2.x = fmaf(v2.x, w2, a2.x); a2.y = fmaf(v2.y, w2, a2.y);
            a3.x = fmaf(v3.x, w3, a3.x); a3.y = fmaf(v3.y, w3, a3.y);
        }
        for (; e < deg; ++e) {
            int oe = __shfl(soff, e);
            float ce = __shfl(coef, e);
            float2 v = *(const float2*)(hb + oe);
            float we = gat ? ce : 1.f;
            a0.x = fmaf(v.x, we, a0.x); a0.y = fmaf(v.y, we, a0.y);
        }
        res.x = (a0.x + a1.x) + (a2.x + a3.x);
        res.y = (a0.y + a1.y) + (a2.y + a3.y);
    } else if (deg > 64) {
        float m = -INF_F, den = 0.f;
        float2 aa = make_float2(0.f, 0.f);
        for (int p = p0; p < p1; ++p) {
            int soff = csr[p];
            float a = a_s[soff >> 9] + adst;
            float att = a >= 0.f ? a : 0.2f * a;
            float mn = fmaxf(m, att);
            float r = __expf(m - mn);
            float w = __expf(att - mn);
            den = den * r + w;
            float2 v = *(const float2*)(hb + soff);
            float reff = gat ? r : 1.f, weff = gat ? w : 1.f;
            aa.x = fmaf(aa.x, reff, weff * v.x);
            aa.y = fmaf(aa.y, reff, weff * v.y);
            m = mn;
        }
        if (gat) { res.x = aa.x / den; res.y = aa.y / den; }
        else     { res = aa; }
    }

    int col = lane * 2;
    float2 ov;
    if (gat) {
        ov.x = res.x + b_a[col];
        ov.y = res.y + b_a[col + 1];
        if (MODE == 0) {
            ov.x = ov.x > 0.f ? ov.x : (__expf(ov.x) - 1.f);
            ov.y = ov.y > 0.f ? ov.y : (__expf(ov.y) - 1.f);
        }
    } else {
        ov.x = dv * res.x + b_g[col - 64];
        ov.y = dv * res.y + b_g[col - 63];
        if (MODE == 0) {
            ov.x = fmaxf(ov.x, 0.f);
            ov.y = fmaxf(ov.y, 0.f);
        }
    }
    *(float2*)&out[(long)node * 128 + col] = ov;
}

// Fused decoder + discriminator. Weights + enc tile all in LDS (~139 KB,
// 1 block/CU). Main loop is pure LDS+VALU (no global loads). sd1 aliases senc.
__global__ __launch_bounds__(512) void k_dense3(
    const float* __restrict__ enc,
    const float* __restrict__ Wdec, const float* __restrict__ bdec,
    const float* __restrict__ Wd1, const float* __restrict__ bd1,
    const float* __restrict__ Wd2, const float* __restrict__ bd2,
    const float* __restrict__ Wd3, const float* __restrict__ bd3,
    float* __restrict__ recon, float* __restrict__ disc, int N)
{
    __shared__ float sWdec[128 * 128];             // 64 KB
    __shared__ float sWd1[128 * 64];               // 32 KB
    __shared__ float sWd2[64 * 32];                // 8 KB
    __shared__ float sWd3v[32];
    __shared__ float senc[64 * 128];               // 32 KB; sd1 aliases later
    int t = threadIdx.x;
    int base = blockIdx.x * 64;
    for (int i = t; i < 4096; i += 512) ((float4*)sWdec)[i] = ((const float4*)Wdec)[i];
    for (int i = t; i < 2048; i += 512) {
        ((float4*)sWd1)[i] = ((const float4*)Wd1)[i];
        // enc tile: 64 rows x 32 float4, coalesced
        int node = i >> 5;
        int gn = base + node;
        float4 v = make_float4(0.f, 0.f, 0.f, 0.f);
        if (gn < N) v = ((const float4*)enc)[(long)gn * 32 + (i & 31)];
        ((float4*)senc)[i] = v;
    }
    if (t < 512) ((float4*)sWd2)[t] = ((const float4*)Wd2)[t];
    if (t < 32) sWd3v[t] = Wd3[t];
    __syncthreads();
    int tx = t & 31, ny = t >> 5;                  // 16 groups x 4 nodes
    int jc = tx * 4, jc2 = tx * 2;
    int gn0 = base + ny * 4;
    const float* xrow = &senc[ny * 4 * 128];

    // Fused A+B: acc = enc@Wdec (4 cols), acc2 = enc@Wd1 (2 cols)
    float acc[4][4], acc2[4][2];
#pragma unroll
    for (int n = 0; n < 4; ++n) {
        acc[n][0] = acc[n][1] = acc[n][2] = acc[n][3] = 0.f;
        acc2[n][0] = acc2[n][1] = 0.f;
    }
#pragma unroll 2
    for (int k0 = 0; k0 < 128; k0 += 4) {
        float4 wd[4]; float2 w1[4];
#pragma unroll
        for (int kk = 0; kk < 4; ++kk) {
            wd[kk] = *(const float4*)&sWdec[(k0 + kk) * 128 + jc];
            w1[kk] = *(const float2*)&sWd1[(k0 + kk) * 64 + jc2];
        }
        float4 xr[4];
#pragma unroll
        for (int n = 0; n < 4; ++n) xr[n] = *(const float4*)&xrow[n * 128 + k0];
#pragma unroll
        for (int kk = 0; kk < 4; ++kk) {
#pragma unroll
            for (int n = 0; n < 4; ++n) {
                float xv = (&xr[n].x)[kk];
                acc[n][0] = fmaf(xv, wd[kk].x, acc[n][0]);
                acc[n][1] = fmaf(xv, wd[kk].y, acc[n][1]);
                acc[n][2] = fmaf(xv, wd[kk].z, acc[n][2]);
                acc[n][3] = fmaf(xv, wd[kk].w, acc[n][3]);
                acc2[n][0] = fmaf(xv, w1[kk].x, acc2[n][0]);
                acc2[n][1] = fmaf(xv, w1[kk].y, acc2[n][1]);
            }
        }
    }
    {   // recon epilogue
        float4 bd = *(const float4*)&bdec[jc];
#pragma unroll
        for (int n = 0; n < 4; ++n) {
            int gn = gn0 + n;
            if (gn < N) {
                *(float4*)&recon[(long)gn * 128 + jc] = make_float4(
                    fmaxf(acc[n][0] + bd.x, 0.f), fmaxf(acc[n][1] + bd.y, 0.f),
                    fmaxf(acc[n][2] + bd.z, 0.f), fmaxf(acc[n][3] + bd.w, 0.f));
            }
        }
    }
    __syncthreads();                               // all senc reads complete
    float* sd1 = senc;                             // alias d1-tile over senc
    {   // d1 -> LDS
        float b1x = bd1[jc2], b1y = bd1[jc2 + 1];
#pragma unroll
        for (int n = 0; n < 4; ++n) {
            float2 v = make_float2(fmaxf(acc2[n][0] + b1x, 0.f), fmaxf(acc2[n][1] + b1y, 0.f));
            *(float2*)&sd1[(ny * 4 + n) * 64 + jc2] = v;
        }
    }
    __syncthreads();

    // Phase C: d2 = d1 @ Wd2 (32 cols, K=64)
    float acc3[4];
#pragma unroll
    for (int n = 0; n < 4; ++n) acc3[n] = 0.f;
    const float* drow = &sd1[ny * 4 * 64];
#pragma unroll 2
    for (int k0 = 0; k0 < 64; k0 += 4) {
        float w1[4];
#pragma unroll
        for (int kk = 0; kk < 4; ++kk) w1[kk] = sWd2[(k0 + kk) * 32 + tx];
        float4 xr[4];
#pragma unroll
        for (int n = 0; n < 4; ++n) xr[n] = *(const float4*)&drow[n * 64 + k0];
#pragma unroll
        for (int kk = 0; kk < 4; ++kk) {
#pragma unroll
            for (int n = 0; n < 4; ++n) acc3[n] = fmaf((&xr[n].x)[kk], w1[kk], acc3[n]);
        }
    }

    // Phase D: disc
    float b2 = bd2[tx];
    float w3 = sWd3v[tx];
    float b3 = bd3[0];
#pragma unroll
    for (int n = 0; n < 4; ++n) {
        int gn = gn0 + n;
        float v = w3 / (1.f + __expf(-(acc3[n] + b2)));
#pragma unroll
        for (int off = 16; off; off >>= 1) v += __shfl_xor(v, off);
        if (tx == 0 && gn < N) disc[gn] = v + b3;
    }
}

extern "C" void kernel_launch(void* const* d_in, const int* in_sizes, int n_in,
                              void* d_out, int out_size, void* d_ws, size_t ws_size,
                              hipStream_t stream)
{
    const float* features = (const float*)d_in[0];
    const void*  edges    = d_in[1];
    const int*   mask     = (const int*)d_in[2];
    const float* W_gat1 = (const float*)d_in[3];
    const float* a_src1 = (const float*)d_in[4];
    const float* a_dst1 = (const float*)d_in[5];
    const float* b_gat1 = (const float*)d_in[6];
    const float* W_gat2 = (const float*)d_in[7];
    const float* a_src2 = (const float*)d_in[8];
    const float* a_dst2 = (const float*)d_in[9];
    const float* b_gat2 = (const float*)d_in[10];
    const float* W_gcn1 = (const float*)d_in[11];
    const float* b_gcn1 = (const float*)d_in[12];
    const float* W_gcn2 = (const float*)d_in[13];
    const float* b_gcn2 = (const float*)d_in[14];
    const float* W_dec  = (const float*)d_in[15];
    const float* b_dec  = (const float*)d_in[16];
    const float* W_d1   = (const float*)d_in[17];
    const float* b_d1   = (const float*)d_in[18];
    const float* W_d2   = (const float*)d_in[19];
    const float* b_d2   = (const float*)d_in[20];
    const float* W_d3   = (const float*)d_in[21];
    const float* b_d3   = (const float*)d_in[22];

    const int  N = in_sizes[0] / 128;
    const long E = (long)in_sizes[1] / 2;

    size_t nP = ((size_t)N + 255) & ~(size_t)255;
    size_t eP = ((size_t)E + 255) & ~(size_t)255;
    int*   deg       = (int*)d_ws;
    int*   offs      = deg + nP;             // uses N+1
    int*   cursor    = offs + nP + 256;
    float* dinv      = (float*)(cursor + nP);
    float* a_s       = dinv + nP;
    float* a_d       = a_s + nP;
    int*   flag      = (int*)(a_d + nP);
    int*   blockSums = flag + 256;
    int*   blockOff  = blockSums + 1024;
    int*   csr       = blockOff + 1024;      // E
    float* h         = (float*)(csr + eP);   // N*128 interleaved
    float* o         = h + nP * 128;         // N*128 interleaved

    hipMemsetAsync(deg, 0, nP * sizeof(int), stream);
    hipMemsetAsync(cursor, 0, nP * sizeof(int), stream);
    hipMemsetAsync(flag, 0, sizeof(int), stream);

    k_detect<<<16, 256, 0, stream>>>((const int*)edges, 2 * E, flag);

    unsigned eB = (unsigned)((E + 255) / 256);
    k_deg<<<eB, 256, 0, stream>>>(edges, E, flag, deg);

    int nbA = (N + 255) / 256;
    k_scanA<<<nbA, 256, 0, stream>>>(deg, N, offs, blockSums);
    k_scanB<<<1, 1024, 0, stream>>>(blockSums, nbA, blockOff);
    k_scanC<<<nbA, 256, 0, stream>>>(offs, blockOff, deg, dinv, N, E);
    int npp = (N + NSHARD - 1) / NSHARD;
    k_fill<<<eB * NSHARD, 256, 0, stream>>>(edges, E, flag, offs, cursor, csr, npp);

    unsigned dB = (unsigned)((N + 63) / 64);
    unsigned aB = (unsigned)((N + 7) / 8);

    k_dense1<<<dB, 512, 0, stream>>>(features, mask, W_gat1, W_gcn1,
                                     a_src1, a_dst1, dinv,
                                     h, a_s, a_d, N);
    k_agg<0><<<aB, 512, 0, stream>>>(offs, csr, a_s, a_d, dinv, h,
                                     b_gat1, b_gcn1, o, N);
    k_dense2<<<dB, 512, 0, stream>>>(o, W_gat2, W_gcn2,
                                     a_src2, a_dst2, dinv,
                                     h, a_s, a_d, N);
    float* out = (float*)d_out;
    float* enc = out + (long)N * 128;
    k_agg<1><<<aB, 512, 0, stream>>>(offs, csr, a_s, a_d, dinv, h,
                                     b_gat2, b_gcn2, enc, N);
    k_dense3<<<dB, 512, 0, stream>>>(enc, W_dec, b_dec, W_d1, b_d1,
                                     W_d2, b_d2, W_d3, b_d3,
                                     out, out + (long)N * 256, N);
}

// Round 13
// 529.781 us; speedup vs baseline: 1.1752x; 1.1752x over previous
//
#include <hip/hip_runtime.h>
#include <math.h>

// ---------------------------------------------------------------------------
// AFPNNet: masked features -> {2-layer GAT, 2-layer GCN} -> concat(encoded)
//          -> recon = relu(enc@Wdec+b), disc = (sigmoid(relu(enc@Wd1+b)@Wd2+b))@Wd3+b
// Outputs flat: recon [N*128] | encoded [N*128] | disc [N]
// h layout: interleaved BF16 [N][128] = [h_gat(64) | h_gcn*dinv_src(64)],
//   256 B/row. csr stores BYTE offsets (src*256). Gathered payload is bf16
//   (halves k_agg's L3 traffic, the largest cost); softmax scalars a_s/a_d,
//   coefs, accumulation all stay f32.
// LESSON (r4-r7): global weight loads in const-trip k-loops are either hoisted
//   (spill) or sunk (serialized) by the scheduler -> stage weights in LDS.
// LESSON (r8/r9): k_fill 16x write amplification = cross-XCD dirty-line
//   replication -> dst-shard by blockIdx&7 (one XCD per csr region).
// LESSON (r9/r12): dense3 is DS/VALU co-limited (12KB LDS reads per 96-FMA
//   quad x 8 waves = 384cyc DS = 384cyc VALU); adding enc to LDS (r12) or
//   2-pass split (r9) both REGRESS. r11 fused version (125us) is best known.
// ---------------------------------------------------------------------------

#define INF_F __int_as_float(0x7f800000)
#define NSHARD 8

__device__ __forceinline__ long edge_at(const void* p, int is64, long i) {
    if (is64) return (long)((const long long*)p)[i];
    return (long)((const int*)p)[i];
}

__device__ __forceinline__ unsigned short f2bf(float f) {   // RNE f32->bf16
    unsigned u = __float_as_uint(f);
    return (unsigned short)((u + 0x7FFFu + ((u >> 16) & 1u)) >> 16);
}
__device__ __forceinline__ float bflo(unsigned p) { return __uint_as_float(p << 16); }
__device__ __forceinline__ float bfhi(unsigned p) { return __uint_as_float(p & 0xFFFF0000u); }

__global__ void k_detect(const int* ew, long words, int* flag) {
    long t = (long)blockIdx.x * blockDim.x + threadIdx.x;
    long stride = words / 8192; if (stride < 1) stride = 1;
    long w = 2 * (t * stride) + 1;
    if (t < 4096 && w < words) {
        if (ew[w] != 0) atomicOr(flag, 1);
    }
}

__global__ void k_deg(const void* edges, long E, const int* flag, int* deg) {
    long e = (long)blockIdx.x * blockDim.x + threadIdx.x;
    if (e >= E) return;
    int is64 = (*flag == 0);
    int d = (int)edge_at(edges, is64, E + e);
    atomicAdd(&deg[d], 1);
}

__global__ void k_scanA(const int* deg, int N, int* offs, int* blockSums) {
    __shared__ int s[256];
    int t = threadIdx.x;
    int i = blockIdx.x * 256 + t;
    int v = (i < N) ? deg[i] : 0;
    s[t] = v;
    for (int off = 1; off < 256; off <<= 1) {
        __syncthreads();
        int u = (t >= off) ? s[t - off] : 0;
        __syncthreads();
        s[t] += u;
    }
    __syncthreads();
    if (i < N) offs[i] = s[t] - v;
    if (t == 255) blockSums[blockIdx.x] = s[255];
}

__global__ void k_scanB(const int* blockSums, int nb, int* blockOff) {
    __shared__ int s[1024];
    int t = threadIdx.x;
    int v = (t < nb) ? blockSums[t] : 0;
    s[t] = v;
    for (int off = 1; off < 1024; off <<= 1) {
        __syncthreads();
        int u = (t >= off) ? s[t - off] : 0;
        __syncthreads();
        s[t] += u;
    }
    __syncthreads();
    if (t < nb) blockOff[t] = s[t] - v;
}

__global__ void k_scanC(int* offs, const int* blockOff, const int* deg,
                        float* dinv, int N, long E) {
    int i = blockIdx.x * 256 + threadIdx.x;
    if (i < N) {
        offs[i] += blockOff[i >> 8];
        int dg = deg[i];
        dinv[i] = dg > 0 ? rsqrtf((float)dg) : 0.0f;
    }
    if (i == 0) offs[N] = (int)E;
}

// XCD-sharded CSR fill (see header LESSON r8/r9).
__global__ void k_fill(const void* edges, long E, const int* flag,
                       const int* offs, int* cursor, int* csr_src, int npp) {
    int bid = blockIdx.x;
    int shard = bid & (NSHARD - 1);
    long e = (long)(bid >> 3) * blockDim.x + threadIdx.x;
    if (e >= E) return;
    int is64 = (*flag == 0);
    int d = (int)edge_at(edges, is64, E + e);
    if (d / npp != shard) return;
    int s = (int)edge_at(edges, is64, e);
    int pos = offs[d] + atomicAdd(&cursor[d], 1);
    csr_src[pos] = s << 8;                 // byte offset into [N][128] bf16 rows
}

// Dense layer 1: K=128 -> h[gn][0:64]=x@Wa, h[gn][64:128]=(x@Wg)*dinv[gn]; bf16 out.
__global__ __launch_bounds__(512) void k_dense1(
    const float* __restrict__ x, const int* __restrict__ mask,
    const float* __restrict__ Wa, const float* __restrict__ Wg,
    const float* __restrict__ aSrc, const float* __restrict__ aDst,
    const float* __restrict__ dinv,
    unsigned short* __restrict__ h16,
    float* __restrict__ a_s, float* __restrict__ a_d, int N)
{
    __shared__ float sW[8192 + 16 + 8192];         // Wa | pad | Wg, 64.1 KB
    int t = threadIdx.x;
    for (int i = t; i < 2048; i += 512) {
        ((float4*)sW)[i] = ((const float4*)Wa)[i];
        ((float4*)(sW + 8208))[i] = ((const float4*)Wg)[i];
    }
    __syncthreads();
    int base = blockIdx.x * 64;
    int tx = t & 31, ny = t >> 5;                  // 16 groups x 4 nodes
    bool gat = tx < 16;
    int jc = (tx & 15) * 4;
    const float* Wp = gat ? sW : (sW + 8208);
    int gn0 = base + ny * 4;
    const float4* xp[4]; float mz[4];
#pragma unroll
    for (int n = 0; n < 4; ++n) {
        int gn = gn0 + n;
        int cl = (gn < N) ? gn : 0;
        xp[n] = (const float4*)(x + (long)cl * 128);
        mz[n] = (gn < N && mask[cl] != 1) ? 1.f : 0.f;
    }
    float acc[4][4];
#pragma unroll
    for (int n = 0; n < 4; ++n) { acc[n][0] = acc[n][1] = acc[n][2] = acc[n][3] = 0.f; }
#pragma unroll 2
    for (int k0 = 0; k0 < 128; k0 += 4) {
        float4 w[4];
#pragma unroll
        for (int kk = 0; kk < 4; ++kk) w[kk] = *(const float4*)&Wp[(k0 + kk) * 64 + jc];
        float4 xr[4];
#pragma unroll
        for (int n = 0; n < 4; ++n) xr[n] = xp[n][k0 >> 2];
#pragma unroll
        for (int kk = 0; kk < 4; ++kk) {
#pragma unroll
            for (int n = 0; n < 4; ++n) {
                float xv = (&xr[n].x)[kk];
                acc[n][0] = fmaf(xv, w[kk].x, acc[n][0]);
                acc[n][1] = fmaf(xv, w[kk].y, acc[n][1]);
                acc[n][2] = fmaf(xv, w[kk].z, acc[n][2]);
                acc[n][3] = fmaf(xv, w[kk].w, acc[n][3]);
            }
        }
    }
#pragma unroll
    for (int n = 0; n < 4; ++n) {
        acc[n][0] *= mz[n]; acc[n][1] *= mz[n]; acc[n][2] *= mz[n]; acc[n][3] *= mz[n];
    }
    float4 as4 = make_float4(0.f, 0.f, 0.f, 0.f), ad4 = as4;
    if (gat) { as4 = *(const float4*)&aSrc[jc]; ad4 = *(const float4*)&aDst[jc]; }
#pragma unroll
    for (int n = 0; n < 4; ++n) {
        int gn = gn0 + n;
        float pa = acc[n][0] * as4.x + acc[n][1] * as4.y + acc[n][2] * as4.z + acc[n][3] * as4.w;
        float pd = acc[n][0] * ad4.x + acc[n][1] * ad4.y + acc[n][2] * ad4.z + acc[n][3] * ad4.w;
#pragma unroll
        for (int off = 8; off; off >>= 1) { pa += __shfl_xor(pa, off); pd += __shfl_xor(pd, off); }
        if (gn < N) {
            if (gat) {
                if (tx == 0) { a_s[gn] = pa; a_d[gn] = pd; }
                ushort4 pk;
                pk.x = f2bf(acc[n][0]); pk.y = f2bf(acc[n][1]);
                pk.z = f2bf(acc[n][2]); pk.w = f2bf(acc[n][3]);
                *(ushort4*)&h16[(long)gn * 128 + jc] = pk;
            } else {
                float dv = dinv[gn];
                ushort4 pk;
                pk.x = f2bf(acc[n][0] * dv); pk.y = f2bf(acc[n][1] * dv);
                pk.z = f2bf(acc[n][2] * dv); pk.w = f2bf(acc[n][3] * dv);
                *(ushort4*)&h16[(long)gn * 128 + 64 + jc] = pk;
            }
        }
    }
}

// Dense layer 2: input o interleaved f32 [N][128], K=64 per branch; bf16 out.
__global__ __launch_bounds__(512) void k_dense2(
    const float* __restrict__ o,
    const float* __restrict__ Wa, const float* __restrict__ Wg,
    const float* __restrict__ aSrc, const float* __restrict__ aDst,
    const float* __restrict__ dinv,
    unsigned short* __restrict__ h16,
    float* __restrict__ a_s, float* __restrict__ a_d, int N)
{
    __shared__ float sW[4096 + 16 + 4096];         // Wa | pad | Wg, 32.1 KB
    int t = threadIdx.x;
    for (int i = t; i < 1024; i += 512) {
        ((float4*)sW)[i] = ((const float4*)Wa)[i];
        ((float4*)(sW + 4112))[i] = ((const float4*)Wg)[i];
    }
    __syncthreads();
    int base = blockIdx.x * 64;
    int tx = t & 31, ny = t >> 5;
    bool gat = tx < 16;
    int jc = (tx & 15) * 4;
    const float* Wp = gat ? sW : (sW + 4112);
    int xoff = gat ? 0 : 16;                       // float4 offset into o row
    int gn0 = base + ny * 4;
    const float4* xp[4];
#pragma unroll
    for (int n = 0; n < 4; ++n) {
        int gn = gn0 + n;
        int cl = (gn < N) ? gn : 0;
        xp[n] = (const float4*)(o + (long)cl * 128) + xoff;
    }
    float acc[4][4];
#pragma unroll
    for (int n = 0; n < 4; ++n) { acc[n][0] = acc[n][1] = acc[n][2] = acc[n][3] = 0.f; }
#pragma unroll 2
    for (int k0 = 0; k0 < 64; k0 += 4) {
        float4 w[4];
#pragma unroll
        for (int kk = 0; kk < 4; ++kk) w[kk] = *(const float4*)&Wp[(k0 + kk) * 64 + jc];
        float4 xr[4];
#pragma unroll
        for (int n = 0; n < 4; ++n) xr[n] = xp[n][k0 >> 2];
#pragma unroll
        for (int kk = 0; kk < 4; ++kk) {
#pragma unroll
            for (int n = 0; n < 4; ++n) {
                float xv = (&xr[n].x)[kk];
                acc[n][0] = fmaf(xv, w[kk].x, acc[n][0]);
                acc[n][1] = fmaf(xv, w[kk].y, acc[n][1]);
                acc[n][2] = fmaf(xv, w[kk].z, acc[n][2]);
                acc[n][3] = fmaf(xv, w[kk].w, acc[n][3]);
            }
        }
    }
    float4 as4 = make_float4(0.f, 0.f, 0.f, 0.f), ad4 = as4;
    if (gat) { as4 = *(const float4*)&aSrc[jc]; ad4 = *(const float4*)&aDst[jc]; }
#pragma unroll
    for (int n = 0; n < 4; ++n) {
        int gn = gn0 + n;
        float pa = acc[n][0] * as4.x + acc[n][1] * as4.y + acc[n][2] * as4.z + acc[n][3] * as4.w;
        float pd = acc[n][0] * ad4.x + acc[n][1] * ad4.y + acc[n][2] * ad4.z + acc[n][3] * ad4.w;
#pragma unroll
        for (int off = 8; off; off >>= 1) { pa += __shfl_xor(pa, off); pd += __shfl_xor(pd, off); }
        if (gn < N) {
            if (gat) {
                if (tx == 0) { a_s[gn] = pa; a_d[gn] = pd; }
                ushort4 pk;
                pk.x = f2bf(acc[n][0]); pk.y = f2bf(acc[n][1]);
                pk.z = f2bf(acc[n][2]); pk.w = f2bf(acc[n][3]);
                *(ushort4*)&h16[(long)gn * 128 + jc] = pk;
            } else {
                float dv = dinv[gn];
                ushort4 pk;
                pk.x = f2bf(acc[n][0] * dv); pk.y = f2bf(acc[n][1] * dv);
                pk.z = f2bf(acc[n][2] * dv); pk.w = f2bf(acc[n][3] * dv);
                *(ushort4*)&h16[(long)gn * 128 + 64 + jc] = pk;
            }
        }
    }
}

// Fused aggregation, wave per dst node. h rows are bf16 (256 B); each lane
// gathers one 4B word = 2 bf16 cols. All math in f32.
template <int MODE>   // 0: layer1 (ELU/ReLU), 1: layer2 (plain)
__global__ __launch_bounds__(512) void k_agg(
    const int* __restrict__ offs, const int* __restrict__ csr,
    const float* __restrict__ a_s, const float* __restrict__ a_d,
    const float* __restrict__ dinv,
    const unsigned short* __restrict__ h16,
    const float* __restrict__ b_a, const float* __restrict__ b_g,
    float* __restrict__ out, int N)
{
    int node = blockIdx.x * 8 + (threadIdx.x >> 6);
    int lane = threadIdx.x & 63;
    if (node >= N) return;
    int p0 = offs[node], p1 = offs[node + 1];
    int deg = p1 - p0;
    float adst = a_d[node];
    float dv = dinv[node];
    bool gat = lane < 32;
    const char* hb = (const char*)h16 + lane * 4;

    float2 res = make_float2(0.f, 0.f);
    if (deg > 0 && deg <= 64) {
        int soff = (lane < deg) ? csr[p0 + lane] : 0;
        float att = -INF_F;
        if (lane < deg) {
            float a = a_s[soff >> 8] + adst;
            att = a >= 0.f ? a : 0.2f * a;
        }
        float m = att;
#pragma unroll
        for (int off = 32; off; off >>= 1) m = fmaxf(m, __shfl_xor(m, off));
        float w = (lane < deg) ? __expf(att - m) : 0.f;
        float den = w;
#pragma unroll
        for (int off = 32; off; off >>= 1) den += __shfl_xor(den, off);
        float coef = w / den;

        float2 a0 = make_float2(0.f, 0.f), a1 = a0, a2 = a0, a3 = a0;
        int e = 0;
        for (; e + 4 <= deg; e += 4) {
            int o0 = __shfl(soff, e),     o1 = __shfl(soff, e + 1);
            int o2 = __shfl(soff, e + 2), o3 = __shfl(soff, e + 3);
            float c0 = __shfl(coef, e),     c1 = __shfl(coef, e + 1);
            float c2 = __shfl(coef, e + 2), c3 = __shfl(coef, e + 3);
            unsigned v0 = *(const unsigned*)(hb + o0);
            unsigned v1 = *(const unsigned*)(hb + o1);
            unsigned v2 = *(const unsigned*)(hb + o2);
            unsigned v3 = *(const unsigned*)(hb + o3);
            float w0 = gat ? c0 : 1.f, w1 = gat ? c1 : 1.f;
            float w2 = gat ? c2 : 1.f, w3 = gat ? c3 : 1.f;
            a0.x = fmaf(bflo(v0), w0, a0.x); a0.y = fmaf(bfhi(v0), w0, a0.y);
            a1.x = fmaf(bflo(v1), w1, a1.x); a1.y = fmaf(bfhi(v1), w1, a1.y);
            a2.x = fmaf(bflo(v2), w2, a2.x); a2.y = fmaf(bfhi(v2), w2, a2.y);
            a3.x = fmaf(bflo(v3), w3, a3.x); a3.y = fmaf(bfhi(v3), w3, a3.y);
        }
        for (; e < deg; ++e) {
            int oe = __shfl(soff, e);
            float ce = __shfl(coef, e);
            unsigned v = *(const unsigned*)(hb + oe);
            float we = gat ? ce : 1.f;
            a0.x = fmaf(bflo(v), we, a0.x); a0.y = fmaf(bfhi(v), we, a0.y);
        }
        res.x = (a0.x + a1.x) + (a2.x + a3.x);
        res.y = (a0.y + a1.y) + (a2.y + a3.y);
    } else if (deg > 64) {
        float m = -INF_F, den = 0.f;
        float2 aa = make_float2(0.f, 0.f);
        for (int p = p0; p < p1; ++p) {
            int soff = csr[p];
            float a = a_s[soff >> 8] + adst;
            float att = a >= 0.f ? a : 0.2f * a;
            float mn = fmaxf(m, att);
            float r = __expf(m - mn);
            float w = __expf(att - mn);
            den = den * r + w;
            unsigned v = *(const unsigned*)(hb + soff);
            float reff = gat ? r : 1.f, weff = gat ? w : 1.f;
            aa.x = fmaf(aa.x, reff, weff * bflo(v));
            aa.y = fmaf(aa.y, reff, weff * bfhi(v));
            m = mn;
        }
        if (gat) { res.x = aa.x / den; res.y = aa.y / den; }
        else     { res = aa; }
    }

    int col = lane * 2;
    float2 ov;
    if (gat) {
        ov.x = res.x + b_a[col];
        ov.y = res.y + b_a[col + 1];
        if (MODE == 0) {
            ov.x = ov.x > 0.f ? ov.x : (__expf(ov.x) - 1.f);
            ov.y = ov.y > 0.f ? ov.y : (__expf(ov.y) - 1.f);
        }
    } else {
        ov.x = dv * res.x + b_g[col - 64];
        ov.y = dv * res.y + b_g[col - 63];
        if (MODE == 0) {
            ov.x = fmaxf(ov.x, 0.f);
            ov.y = fmaxf(ov.y, 0.f);
        }
    }
    *(float2*)&out[(long)node * 128 + col] = ov;
}

// Fused decoder + discriminator (r11 version — best measured: 125us).
// All weights in LDS (~120 KB, 1 block/CU); phases A+B fused, one enc pass.
__global__ __launch_bounds__(512) void k_dense3(
    const float* __restrict__ enc,
    const float* __restrict__ Wdec, const float* __restrict__ bdec,
    const float* __restrict__ Wd1, const float* __restrict__ bd1,
    const float* __restrict__ Wd2, const float* __restrict__ bd2,
    const float* __restrict__ Wd3, const float* __restrict__ bd3,
    float* __restrict__ recon, float* __restrict__ disc, int N)
{
    __shared__ float sWdec[128 * 128];             // 64 KB
    __shared__ float sWd1[128 * 64];               // 32 KB
    __shared__ float sWd2[64 * 32];                // 8 KB
    __shared__ float sWd3v[32];
    __shared__ float sd1[64 * 64];                 // 16 KB
    int t = threadIdx.x;
    for (int i = t; i < 4096; i += 512) ((float4*)sWdec)[i] = ((const float4*)Wdec)[i];
    for (int i = t; i < 2048; i += 512) ((float4*)sWd1)[i] = ((const float4*)Wd1)[i];
    if (t < 512) ((float4*)sWd2)[t] = ((const float4*)Wd2)[t];
    if (t < 32) sWd3v[t] = Wd3[t];
    __syncthreads();
    int base = blockIdx.x * 64;
    int tx = t & 31, ny = t >> 5;                  // 16 groups x 4 nodes
    int jc = tx * 4, jc2 = tx * 2;
    int gn0 = base + ny * 4;
    const float4* ep[4];
#pragma unroll
    for (int n = 0; n < 4; ++n) {
        int gn = gn0 + n;
        int cl = (gn < N) ? gn : 0;
        ep[n] = (const float4*)(enc + (long)cl * 128);
    }

    // Fused A+B: acc = enc@Wdec (4 cols), acc2 = enc@Wd1 (2 cols)
    float acc[4][4], acc2[4][2];
#pragma unroll
    for (int n = 0; n < 4; ++n) {
        acc[n][0] = acc[n][1] = acc[n][2] = acc[n][3] = 0.f;
        acc2[n][0] = acc2[n][1] = 0.f;
    }
#pragma unroll 2
    for (int k0 = 0; k0 < 128; k0 += 4) {
        float4 wd[4]; float2 w1[4];
#pragma unroll
        for (int kk = 0; kk < 4; ++kk) {
            wd[kk] = *(const float4*)&sWdec[(k0 + kk) * 128 + jc];
            w1[kk] = *(const float2*)&sWd1[(k0 + kk) * 64 + jc2];
        }
        float4 xr[4];
#pragma unroll
        for (int n = 0; n < 4; ++n) xr[n] = ep[n][k0 >> 2];
#pragma unroll
        for (int kk = 0; kk < 4; ++kk) {
#pragma unroll
            for (int n = 0; n < 4; ++n) {
                float xv = (&xr[n].x)[kk];
                acc[n][0] = fmaf(xv, wd[kk].x, acc[n][0]);
                acc[n][1] = fmaf(xv, wd[kk].y, acc[n][1]);
                acc[n][2] = fmaf(xv, wd[kk].z, acc[n][2]);
                acc[n][3] = fmaf(xv, wd[kk].w, acc[n][3]);
                acc2[n][0] = fmaf(xv, w1[kk].x, acc2[n][0]);
                acc2[n][1] = fmaf(xv, w1[kk].y, acc2[n][1]);
            }
        }
    }
    {   // recon epilogue
        float4 bd = *(const float4*)&bdec[jc];
#pragma unroll
        for (int n = 0; n < 4; ++n) {
            int gn = gn0 + n;
            if (gn < N) {
                *(float4*)&recon[(long)gn * 128 + jc] = make_float4(
                    fmaxf(acc[n][0] + bd.x, 0.f), fmaxf(acc[n][1] + bd.y, 0.f),
                    fmaxf(acc[n][2] + bd.z, 0.f), fmaxf(acc[n][3] + bd.w, 0.f));
            }
        }
    }
    {   // d1 -> LDS
        float b1x = bd1[jc2], b1y = bd1[jc2 + 1];
#pragma unroll
        for (int n = 0; n < 4; ++n) {
            float2 v = make_float2(fmaxf(acc2[n][0] + b1x, 0.f), fmaxf(acc2[n][1] + b1y, 0.f));
            *(float2*)&sd1[(ny * 4 + n) * 64 + jc2] = v;
        }
    }
    __syncthreads();

    // Phase C: d2 = d1 @ Wd2 (32 cols, K=64)
    float acc3[4];
#pragma unroll
    for (int n = 0; n < 4; ++n) acc3[n] = 0.f;
    const float* drow = &sd1[ny * 4 * 64];
#pragma unroll 2
    for (int k0 = 0; k0 < 64; k0 += 4) {
        float w1[4];
#pragma unroll
        for (int kk = 0; kk < 4; ++kk) w1[kk] = sWd2[(k0 + kk) * 32 + tx];
        float4 xr[4];
#pragma unroll
        for (int n = 0; n < 4; ++n) xr[n] = *(const float4*)&drow[n * 64 + k0];
#pragma unroll
        for (int kk = 0; kk < 4; ++kk) {
#pragma unroll
            for (int n = 0; n < 4; ++n) acc3[n] = fmaf((&xr[n].x)[kk], w1[kk], acc3[n]);
        }
    }

    // Phase D: disc
    float b2 = bd2[tx];
    float w3 = sWd3v[tx];
    float b3 = bd3[0];
#pragma unroll
    for (int n = 0; n < 4; ++n) {
        int gn = gn0 + n;
        float v = w3 / (1.f + __expf(-(acc3[n] + b2)));
#pragma unroll
        for (int off = 16; off; off >>= 1) v += __shfl_xor(v, off);
        if (tx == 0 && gn < N) disc[gn] = v + b3;
    }
}

extern "C" void kernel_launch(void* const* d_in, const int* in_sizes, int n_in,
                              void* d_out, int out_size, void* d_ws, size_t ws_size,
                              hipStream_t stream)
{
    const float* features = (const float*)d_in[0];
    const void*  edges    = d_in[1];
    const int*   mask     = (const int*)d_in[2];
    const float* W_gat1 = (const float*)d_in[3];
    const float* a_src1 = (const float*)d_in[4];
    const float* a_dst1 = (const float*)d_in[5];
    const float* b_gat1 = (const float*)d_in[6];
    const float* W_gat2 = (const float*)d_in[7];
    const float* a_src2 = (const float*)d_in[8];
    const float* a_dst2 = (const float*)d_in[9];
    const float* b_gat2 = (const float*)d_in[10];
    const float* W_gcn1 = (const float*)d_in[11];
    const float* b_gcn1 = (const float*)d_in[12];
    const float* W_gcn2 = (const float*)d_in[13];
    const float* b_gcn2 = (const float*)d_in[14];
    const float* W_dec  = (const float*)d_in[15];
    const float* b_dec  = (const float*)d_in[16];
    const float* W_d1   = (const float*)d_in[17];
    const float* b_d1   = (const float*)d_in[18];
    const float* W_d2   = (const float*)d_in[19];
    const float* b_d2   = (const float*)d_in[20];
    const float* W_d3   = (const float*)d_in[21];
    const float* b_d3   = (const float*)d_in[22];

    const int  N = in_sizes[0] / 128;
    const long E = (long)in_sizes[1] / 2;

    size_t nP = ((size_t)N + 255) & ~(size_t)255;
    size_t eP = ((size_t)E + 255) & ~(size_t)255;
    int*   deg       = (int*)d_ws;
    int*   offs      = deg + nP;             // uses N+1
    int*   cursor    = offs + nP + 256;
    float* dinv      = (float*)(cursor + nP);
    float* a_s       = dinv + nP;
    float* a_d       = a_s + nP;
    int*   flag      = (int*)(a_d + nP);
    int*   blockSums = flag + 256;
    int*   blockOff  = blockSums + 1024;
    int*   csr       = blockOff + 1024;      // E
    unsigned short* h16 = (unsigned short*)(csr + eP);   // N*128 bf16
    float* o         = (float*)(csr + eP) + nP * 64;     // N*128 f32 (after h16)

    hipMemsetAsync(deg, 0, nP * sizeof(int), stream);
    hipMemsetAsync(cursor, 0, nP * sizeof(int), stream);
    hipMemsetAsync(flag, 0, sizeof(int), stream);

    k_detect<<<16, 256, 0, stream>>>((const int*)edges, 2 * E, flag);

    unsigned eB = (unsigned)((E + 255) / 256);
    k_deg<<<eB, 256, 0, stream>>>(edges, E, flag, deg);

    int nbA = (N + 255) / 256;
    k_scanA<<<nbA, 256, 0, stream>>>(deg, N, offs, blockSums);
    k_scanB<<<1, 1024, 0, stream>>>(blockSums, nbA, blockOff);
    k_scanC<<<nbA, 256, 0, stream>>>(offs, blockOff, deg, dinv, N, E);
    int npp = (N + NSHARD - 1) / NSHARD;
    k_fill<<<eB * NSHARD, 256, 0, stream>>>(edges, E, flag, offs, cursor, csr, npp);

    unsigned dB = (unsigned)((N + 63) / 64);
    unsigned aB = (unsigned)((N + 7) / 8);

    k_dense1<<<dB, 512, 0, stream>>>(features, mask, W_gat1, W_gcn1,
                                     a_src1, a_dst1, dinv,
                                     h16, a_s, a_d, N);
    k_agg<0><<<aB, 512, 0, stream>>>(offs, csr, a_s, a_d, dinv, h16,
                                     b_gat1, b_gcn1, o, N);
    k_dense2<<<dB, 512, 0, stream>>>(o, W_gat2, W_gcn2,
                                     a_src2, a_dst2, dinv,
                                     h16, a_s, a_d, N);
    float* out = (float*)d_out;
    float* enc = out + (long)N * 128;
    k_agg<1><<<aB, 512, 0, stream>>>(offs, csr, a_s, a_d, dinv, h16,
                                     b_gat2, b_gcn2, enc, N);
    k_dense3<<<dB, 512, 0, stream>>>(enc, W_dec, b_dec, W_d1, b_d1,
                                     W_d2, b_d2, W_d3, b_d3,
                                     out, out + (long)N * 256, N);
}